// Round 1
// baseline (2053.792 us; speedup 1.0000x reference)
//
#include <hip/hip_runtime.h>
#include <hip/hip_bf16.h>

#define N_ 32
#define C_ 64
#define T_ 256
#define V_ 25
#define O_ 192
#define S_ 3
#define R_ 8
#define VV (V_*V_)      // 625
#define TV (T_*V_)      // 6400
#define NTV (N_*T_*V_)  // 204800

// workspace layout (float units)
#define WS_AAT   0                              // N*S*O*VV = 11,520,000
#define WS_XD    (WS_AAT + N_*S_*O_*VV)         // N*O*TV  = 39,321,600
#define WS_XM    (WS_XD + (size_t)N_*O_*TV)     // N*C*V   = 51,200
#define WS_STAT  (WS_XM + N_*C_*V_)             // 4*O_ : ysum, ysq, dsum, dsq
#define WS_COEF  (WS_STAT + 4*O_)               // 4*O_ : ay, by, ad, bd
// total ≈ 50.9M floats ≈ 204 MB

// ---------------- K1: xm[n,c,v] = mean_t x[n,c,t,v] ----------------
__global__ void k1_xm(const float* __restrict__ x, float* __restrict__ ws) {
    __shared__ float ps[256];
    int nc = blockIdx.x;            // n*C_ + c
    int tid = threadIdx.x;
    const float* xp = x + (size_t)nc * TV;
    float acc = 0.f;
    if (tid < 250) {
        int tg = tid / 25, v = tid % 25;
        for (int j = 0; j < 26; ++j) {
            int t = tg + 10 * j;
            if (t < T_) acc += xp[t * V_ + v];
        }
    }
    ps[tid] = acc;
    __syncthreads();
    if (tid < V_) {
        float s = 0.f;
        for (int tg = 0; tg < 10; ++tg) s += ps[tg * 25 + tid];
        ws[WS_XM + (size_t)nc * V_ + tid] = s * (1.f / T_);
    }
}

// ---------------- K2: per (n,s): x1,x2 -> d -> A_at ----------------
__global__ void k2_aat(const float* __restrict__ spd, const float* __restrict__ A3,
                       const float* __restrict__ A6,
                       const float* __restrict__ w1, const float* __restrict__ b1,
                       const float* __restrict__ w2, const float* __restrict__ b2,
                       const float* __restrict__ w4, const float* __restrict__ b4,
                       const float* __restrict__ alpha, const float* __restrict__ beta,
                       const float* __restrict__ gamma, float* __restrict__ ws) {
    __shared__ float xm[C_*V_];          // 1600
    __shared__ float x1s[R_*V_], x2s[R_*V_];
    __shared__ float dm[R_*VV];          // 5000
    __shared__ float a3[VV], sp[VV], a6[6*VV];
    int bid = blockIdx.x;  // n*S_ + s
    int n = bid / S_, s = bid % S_;
    int tid = threadIdx.x;
    const float* xmg = ws + WS_XM + (size_t)n * C_ * V_;
    for (int p = tid; p < C_*V_; p += 256) xm[p] = xmg[p];
    for (int p = tid; p < VV; p += 256) { a3[p] = A3[s*VV + p]; sp[p] = spd[p]; }
    for (int p = tid; p < 6*VV; p += 256) a6[p] = A6[p];
    __syncthreads();
    if (tid < R_*V_) {
        int r = tid / V_, v = tid % V_;
        float acc1 = b1[s*R_ + r], acc2 = b2[s*R_ + r];
        for (int c = 0; c < C_; ++c) {
            float xv = xm[c*V_ + v];
            acc1 += xv * w1[(s*R_ + r)*C_ + c];
            acc2 += xv * w2[(s*R_ + r)*C_ + c];
        }
        x1s[tid] = acc1; x2s[tid] = acc2;
    }
    __syncthreads();
    for (int p = tid; p < R_*VV; p += 256) {
        int r = p / VV, uv = p % VV, u = uv / V_, v = uv % V_;
        dm[p] = tanhf(x1s[r*V_ + u] - x2s[r*V_ + v]);
    }
    __syncthreads();
    float al = alpha[0], be = beta[0], ga = gamma[0];
    float* out = ws + WS_AAT + (size_t)(n*S_ + s) * O_ * VV;
    for (int o = 0; o < O_; ++o) {
        const float* w4p = w4 + (s*O_ + o) * R_;
        float b4v = b4[s*O_ + o];
        const float* a6p = a6 + (o % 6) * VV;
        for (int p = tid; p < VV; p += 256) {
            float acc = b4v;
            #pragma unroll
            for (int r = 0; r < R_; ++r) acc += dm[r*VV + p] * w4p[r];
            out[o*VV + p] = al * acc + a3[p] + be * a6p[p] + ga * sp[p];
        }
    }
}

// ---------------- K3: main fused kernel ----------------
#define TT 8            // t-tile
#define PTS (TT*V_)     // 200
#define OG 8            // o-group

__global__ __launch_bounds__(256, 2)
void k3_main(const float* __restrict__ x,
             const float* __restrict__ w3, const float* __restrict__ b3,
             const float* __restrict__ dw, const float* __restrict__ db,
             float* __restrict__ yraw,   // = d_out (pre-BN y)
             float* __restrict__ ws) {
    __shared__ float xs[C_*PTS];        // 51.2 KB, x[n,:,t-tile,:]
    __shared__ float wbuf[C_*OG];       // [c][r], 2 KB
    __shared__ float abuf[OG*VV];       // 20 KB
    __shared__ float x3s[OG*PTS];       // 6.4 KB
    __shared__ float stat[2*OG];
    int bid = blockIdx.x;
    int n = bid / (T_/TT);
    int tile = bid % (T_/TT);
    int t0 = tile * TT;
    int tid = threadIdx.x;

    const float* xg = x + (size_t)n * C_ * TV + (size_t)t0 * V_;
    for (int p = tid; p < C_*PTS; p += 256) {
        int c = p / PTS, pt = p % PTS;
        xs[p] = xg[(size_t)c * TV + pt];
    }
    const float* aat_n = ws + WS_AAT + (size_t)n * S_ * O_ * VV;
    float* stats = ws + WS_STAT;
    float* xdws = ws + WS_XD;
    __syncthreads();

    for (int og = 0; og < O_/OG; ++og) {
        int o0 = og * OG;
        // ======== y part: y[o,t,u] = sum_s sum_v A_at[n,s,o,u,v]*x3[n,s,o,t,v]
        float yacc[TT];
        #pragma unroll
        for (int t = 0; t < TT; ++t) yacc[t] = 0.f;

        for (int s = 0; s < S_; ++s) {
            for (int p = tid; p < OG*C_; p += 256) {
                int r = p / C_, c = p % C_;
                wbuf[c*OG + r] = w3[(size_t)(s*O_ + o0 + r) * C_ + c];
            }
            for (int p = tid; p < OG*VV; p += 256)
                abuf[p] = aat_n[(size_t)(s*O_ + o0) * VV + p];
            __syncthreads();
            // x3 phase: thread = pt, computes 8 rows
            if (tid < PTS) {
                float acc[OG];
                #pragma unroll
                for (int r = 0; r < OG; ++r) acc[r] = b3[s*O_ + o0 + r];
                for (int c = 0; c < C_; ++c) {
                    float xv = xs[c*PTS + tid];
                    #pragma unroll
                    for (int r = 0; r < OG; ++r) acc[r] += xv * wbuf[c*OG + r];
                }
                #pragma unroll
                for (int r = 0; r < OG; ++r) x3s[r*PTS + tid] = acc[r];
            }
            __syncthreads();
            // contract phase: thread = (o_l,u), A-row cached in regs
            if (tid < OG*V_) {
                int o_l = tid / V_, u = tid % V_;
                float areg[V_];
                #pragma unroll
                for (int v = 0; v < V_; ++v) areg[v] = abuf[o_l*VV + u*V_ + v];
                #pragma unroll
                for (int t = 0; t < TT; ++t) {
                    float acc = 0.f;
                    #pragma unroll
                    for (int v = 0; v < V_; ++v)
                        acc += areg[v] * x3s[o_l*PTS + t*V_ + v];
                    yacc[t] += acc;
                }
            }
            __syncthreads();
        }
        // write y_raw + stats
        if (tid < OG*V_) {
            int o_l = tid / V_, u = tid % V_;
            float* yp = yraw + (size_t)(n*O_ + o0 + o_l) * TV + (size_t)t0 * V_ + u;
            #pragma unroll
            for (int t = 0; t < TT; ++t) yp[t*V_] = yacc[t];
        }
        if (tid < 2*OG) stat[tid] = 0.f;
        __syncthreads();
        {
            float s1 = 0.f, s2 = 0.f;
            #pragma unroll
            for (int t = 0; t < TT; ++t) { s1 += yacc[t]; s2 += yacc[t]*yacc[t]; }
            if (tid < OG*V_) {
                int o_l = tid / V_;
                atomicAdd(&stat[2*o_l],     s1);
                atomicAdd(&stat[2*o_l + 1], s2);
            }
        }
        __syncthreads();
        if (tid < OG) {
            atomicAdd(&stats[0*O_ + o0 + tid], stat[2*tid]);
            atomicAdd(&stats[1*O_ + o0 + tid], stat[2*tid + 1]);
        }
        __syncthreads();
        // ======== down part: xd[o,t,v] = sum_c down_w[o,c]*x + down_b
        for (int p = tid; p < OG*C_; p += 256) {
            int r = p / C_, c = p % C_;
            wbuf[c*OG + r] = dw[(size_t)(o0 + r) * C_ + c];
        }
        __syncthreads();
        float dval[OG];
        if (tid < PTS) {
            #pragma unroll
            for (int r = 0; r < OG; ++r) dval[r] = db[o0 + r];
            for (int c = 0; c < C_; ++c) {
                float xv = xs[c*PTS + tid];
                #pragma unroll
                for (int r = 0; r < OG; ++r) dval[r] += xv * wbuf[c*OG + r];
            }
            float* xdp = xdws + (size_t)(n*O_ + o0) * TV + (size_t)t0 * V_ + tid;
            #pragma unroll
            for (int r = 0; r < OG; ++r) xdp[(size_t)r * TV] = dval[r];
        } else {
            #pragma unroll
            for (int r = 0; r < OG; ++r) dval[r] = 0.f;
        }
        if (tid < 2*OG) stat[tid] = 0.f;
        __syncthreads();
        #pragma unroll
        for (int r = 0; r < OG; ++r) {
            float v1 = dval[r], v2 = dval[r] * dval[r];
            for (int m = 32; m > 0; m >>= 1) {
                v1 += __shfl_xor(v1, m);
                v2 += __shfl_xor(v2, m);
            }
            if ((tid & 63) == 0) {
                atomicAdd(&stat[2*r],     v1);
                atomicAdd(&stat[2*r + 1], v2);
            }
        }
        __syncthreads();
        if (tid < OG) {
            atomicAdd(&stats[2*O_ + o0 + tid], stat[2*tid]);
            atomicAdd(&stats[3*O_ + o0 + tid], stat[2*tid + 1]);
        }
        __syncthreads();
    }
}

// ---------------- K4: finalize BN coefficients ----------------
__global__ void k4_coef(const float* __restrict__ bn_w, const float* __restrict__ bn_b,
                        const float* __restrict__ dbn_w, const float* __restrict__ dbn_b,
                        float* __restrict__ ws) {
    int o = threadIdx.x;
    if (o >= O_) return;
    const float* st = ws + WS_STAT;
    float inv = 1.f / (float)NTV;
    float mu_y  = st[o] * inv;
    float var_y = st[O_ + o] * inv - mu_y * mu_y;
    float ay = bn_w[o] * rsqrtf(var_y + 1e-5f);
    float by = bn_b[o] - mu_y * ay;
    float mu_d  = st[2*O_ + o] * inv;
    float var_d = st[3*O_ + o] * inv - mu_d * mu_d;
    float ad = dbn_w[o] * rsqrtf(var_d + 1e-5f);
    float bd = dbn_b[o] - mu_d * ad;
    float* cf = ws + WS_COEF;
    cf[o] = ay; cf[O_ + o] = by; cf[2*O_ + o] = ad; cf[3*O_ + o] = bd;
}

// ---------------- K5: final elementwise (in-place on d_out) ----------------
__global__ void k5_final(float* __restrict__ out, const float* __restrict__ ws) {
    const float4* d4 = (const float4*)(ws + WS_XD);
    const float* cf = ws + WS_COEF;
    float4* o4 = (float4*)out;
    int total = (int)((size_t)N_ * O_ * TV / 4);
    for (int i = blockIdx.x * blockDim.x + threadIdx.x; i < total;
         i += gridDim.x * blockDim.x) {
        int o = (i / (TV/4)) % O_;
        float ay = cf[o], by = cf[O_ + o], ad = cf[2*O_ + o], bd = cf[3*O_ + o];
        float4 yv = o4[i], dv = d4[i];
        float4 r;
        r.x = fmaxf(ay*yv.x + by + ad*dv.x + bd, 0.f);
        r.y = fmaxf(ay*yv.y + by + ad*dv.y + bd, 0.f);
        r.z = fmaxf(ay*yv.z + by + ad*dv.z + bd, 0.f);
        r.w = fmaxf(ay*yv.w + by + ad*dv.w + bd, 0.f);
        o4[i] = r;
    }
}

extern "C" void kernel_launch(void* const* d_in, const int* in_sizes, int n_in,
                              void* d_out, int out_size, void* d_ws, size_t ws_size,
                              hipStream_t stream) {
    const float* x     = (const float*)d_in[0];
    const float* spd   = (const float*)d_in[1];
    const float* A3    = (const float*)d_in[2];
    const float* A6    = (const float*)d_in[3];
    const float* w1    = (const float*)d_in[4];
    const float* b1    = (const float*)d_in[5];
    const float* w2    = (const float*)d_in[6];
    const float* b2    = (const float*)d_in[7];
    const float* w4    = (const float*)d_in[8];
    const float* b4    = (const float*)d_in[9];
    const float* w3    = (const float*)d_in[10];
    const float* b3    = (const float*)d_in[11];
    const float* alpha = (const float*)d_in[12];
    const float* beta  = (const float*)d_in[13];
    const float* gamma = (const float*)d_in[14];
    const float* bn_w  = (const float*)d_in[15];
    const float* bn_b  = (const float*)d_in[16];
    const float* dw    = (const float*)d_in[17];
    const float* db    = (const float*)d_in[18];
    const float* dbn_w = (const float*)d_in[19];
    const float* dbn_b = (const float*)d_in[20];
    float* out = (float*)d_out;
    float* ws  = (float*)d_ws;

    // zero the stat accumulators (kernel accumulates via atomics each call)
    hipMemsetAsync(ws + WS_STAT, 0, 4 * O_ * sizeof(float), stream);

    k1_xm<<<N_*C_, 256, 0, stream>>>(x, ws);
    k2_aat<<<N_*S_, 256, 0, stream>>>(spd, A3, A6, w1, b1, w2, b2, w4, b4,
                                      alpha, beta, gamma, ws);
    k3_main<<<N_*(T_/TT), 256, 0, stream>>>(x, w3, b3, dw, db, out, ws);
    k4_coef<<<1, 256, 0, stream>>>(bn_w, bn_b, dbn_w, dbn_b, ws);
    k5_final<<<8192, 256, 0, stream>>>(out, ws);
}

// Round 2
// 660.388 us; speedup vs baseline: 3.1100x; 3.1100x over previous
//
#include <hip/hip_runtime.h>

#define N_ 32
#define C_ 64
#define T_ 256
#define V_ 25
#define O_ 192
#define S_ 3
#define R_ 8
#define VV (V_*V_)      // 625
#define TV (T_*V_)      // 6400

typedef unsigned short u16;
typedef __attribute__((ext_vector_type(4))) u16 u16x4;
typedef __attribute__((ext_vector_type(8))) u16 u16x8;
typedef __attribute__((ext_vector_type(8))) __bf16 bf16x8;
typedef __attribute__((ext_vector_type(4))) float f32x4;

// ---- workspace layout ----
// u16 region:
#define WS_A2F_U 0                                   // N*O*3*2*64*8 = 18,874,368
#define WS_XB_U  (18874368)                          // N*TV*C = 13,107,200
#define WS_XD_U  (18874368 + 13107200)               // N*O*TV = 39,321,600
// float region (after 71,303,168 u16 = 142,606,336 B):
#define WS_XM_F   (35651584)                         // N*C*V = 51,200
#define WS_STAT_F (35651584 + 51200)                 // 4*O
#define WS_COEF_F (35651584 + 51200 + 768)           // 4*O

__device__ __forceinline__ u16 f2b(float f) {
    unsigned u = __builtin_bit_cast(unsigned, f);
    unsigned r = (u + 0x7FFFu + ((u >> 16) & 1u)) >> 16;
    return (u16)r;
}
__device__ __forceinline__ float b2f(u16 u) {
    return __builtin_bit_cast(float, ((unsigned)u) << 16);
}
__device__ __forceinline__ f32x4 mfma16(bf16x8 a, bf16x8 b, f32x4 c) {
    return __builtin_amdgcn_mfma_f32_16x16x32_bf16(a, b, c, 0, 0, 0);
}
__device__ __forceinline__ bf16x8 joinfrag(u16x4 lo, u16x4 hi) {
    return __builtin_bit_cast(bf16x8,
        __builtin_shufflevector(lo, hi, 0, 1, 2, 3, 4, 5, 6, 7));
}

// ---------------- K0: x[n,c,t,v] fp32 -> xb[n,(t,v),c] bf16 ----------------
__global__ void k0_xb(const float* __restrict__ x, u16* __restrict__ xb) {
    __shared__ float tile[64 * 65];
    int bid = blockIdx.x;
    int n = bid / 100, tl = bid % 100;
    int tv0 = tl * 64;
    int tid = threadIdx.x;
    for (int p = tid; p < 1024; p += 256) {
        int c = p >> 4, q = p & 15;
        float4 v = *(const float4*)&x[((size_t)(n * 64 + c)) * 6400 + tv0 + q * 4];
        tile[c * 65 + q * 4 + 0] = v.x;
        tile[c * 65 + q * 4 + 1] = v.y;
        tile[c * 65 + q * 4 + 2] = v.z;
        tile[c * 65 + q * 4 + 3] = v.w;
    }
    __syncthreads();
    for (int p = tid; p < 1024; p += 256) {
        int tvl = p >> 4, cq = p & 15;
        u16x4 w;
        #pragma unroll
        for (int i = 0; i < 4; ++i) w[i] = f2b(tile[(cq * 4 + i) * 65 + tvl]);
        *(u16x4*)&xb[((size_t)n * 6400 + tv0 + tvl) * 64 + cq * 4] = w;
    }
}

// ---------------- K1: xm[n,c,v] = mean_t x[n,c,t,v] ----------------
__global__ void k1_xm(const float* __restrict__ x, float* __restrict__ xm_out) {
    __shared__ float ps[256];
    int nc = blockIdx.x;
    int tid = threadIdx.x;
    const float* xp = x + (size_t)nc * TV;
    float acc = 0.f;
    if (tid < 250) {
        int tg = tid / 25, v = tid % 25;
        for (int j = 0; j < 26; ++j) {
            int t = tg + 10 * j;
            if (t < T_) acc += xp[t * V_ + v];
        }
    }
    ps[tid] = acc;
    __syncthreads();
    if (tid < V_) {
        float s = 0.f;
        for (int tg = 0; tg < 10; ++tg) s += ps[tg * 25 + tid];
        xm_out[(size_t)nc * V_ + tid] = s * (1.f / T_);
    }
}

// ---------------- K2: build A2F (frag-swizzled A_at, bf16) ----------------
__global__ void k2_a2f(const float* __restrict__ spd, const float* __restrict__ A3,
                       const float* __restrict__ A6,
                       const float* __restrict__ w1, const float* __restrict__ b1,
                       const float* __restrict__ w2, const float* __restrict__ b2,
                       const float* __restrict__ w4, const float* __restrict__ b4,
                       const float* __restrict__ b3,
                       const float* __restrict__ alpha, const float* __restrict__ beta,
                       const float* __restrict__ gamma,
                       u16* __restrict__ a2f, const float* __restrict__ xmbuf) {
    __shared__ float xm[C_ * V_];
    __shared__ float x1s[R_ * V_], x2s[R_ * V_];
    __shared__ float dm[R_ * VV];
    __shared__ float a3s[VV], sps[VV], a6s[6 * VV];
    __shared__ float aat[2 * VV];
    __shared__ float rsB[2 * V_];
    __shared__ float w4s[2][R_];
    __shared__ float b4s[2];
    int bid = blockIdx.x;
    int n = bid / S_, s = bid % S_;
    int tid = threadIdx.x;
    const float* xmg = xmbuf + (size_t)n * C_ * V_;
    for (int p = tid; p < C_ * V_; p += 256) xm[p] = xmg[p];
    for (int p = tid; p < VV; p += 256) { a3s[p] = A3[s * VV + p]; sps[p] = spd[p]; }
    for (int p = tid; p < 6 * VV; p += 256) a6s[p] = A6[p];
    __syncthreads();
    if (tid < R_ * V_) {
        int r = tid / V_, v = tid % V_;
        float acc1 = b1[s * R_ + r], acc2 = b2[s * R_ + r];
        for (int c = 0; c < C_; ++c) {
            float xv = xm[c * V_ + v];
            acc1 += xv * w1[(s * R_ + r) * C_ + c];
            acc2 += xv * w2[(s * R_ + r) * C_ + c];
        }
        x1s[tid] = acc1; x2s[tid] = acc2;
    }
    __syncthreads();
    for (int p = tid; p < R_ * VV; p += 256) {
        int r = p / VV, uv = p % VV, u = uv / V_, v = uv % V_;
        dm[p] = tanhf(x1s[r * V_ + u] - x2s[r * V_ + v]);
    }
    __syncthreads();
    float al = alpha[0], be = beta[0], ga = gamma[0];
    for (int op = 0; op < O_ / 2; ++op) {
        int o0 = op * 2;
        if (tid < 16) w4s[tid >> 3][tid & 7] =
            w4[((size_t)(s * O_ + o0 + (tid >> 3))) * R_ + (tid & 7)];
        if (tid < 2) b4s[tid] = b4[s * O_ + o0 + tid];
        __syncthreads();
        for (int p = tid; p < 2 * VV; p += 256) {
            int oo = p / VV, pp = p % VV;
            float acc = b4s[oo];
            #pragma unroll
            for (int r = 0; r < R_; ++r) acc += dm[r * VV + pp] * w4s[oo][r];
            int o = o0 + oo;
            aat[p] = al * acc + a3s[pp] + be * a6s[(o % 6) * VV + pp] + ga * sps[pp];
        }
        __syncthreads();
        if (tid < 2 * V_) {
            int oo = tid / V_, u = tid % V_;
            float rs = 0.f;
            for (int v = 0; v < V_; ++v) rs += aat[oo * VV + u * V_ + v];
            rsB[tid] = b3[s * O_ + o0 + oo] * rs;
        }
        __syncthreads();
        {
            int oo = tid >> 7, l2 = tid & 127, cu = l2 >> 6, l = l2 & 63;
            int u = cu * 16 + (l & 15);
            u16x8 w;
            #pragma unroll
            for (int j = 0; j < 8; ++j) {
                int v = ((j >> 2) << 4) + ((l >> 4) << 2) + (j & 3);
                float val = 0.f;
                if (u < V_) {
                    if (v < V_) val = aat[oo * VV + u * V_ + v];
                    else if (v == V_) val = rsB[oo * V_ + u];
                }
                w[j] = f2b(val);
            }
            size_t idx = ((((size_t)(n * O_ + o0 + oo)) * S_ + s) * 2 + cu) * 64 + l;
            ((u16x8*)a2f)[idx] = w;
        }
        __syncthreads();
    }
}

// ---------------- K3: fused MFMA GEMM1+GEMM2 + down + stats ----------------
#define TCH 16
#define OB 16
#define VS 36
#define SSTR (TCH*VS)        // 576
#define OSTR (3*SSTR + 4)    // 1732

__global__ __launch_bounds__(256, 1)
void k3_main(const u16* __restrict__ xb,
             const float* __restrict__ w3, const float* __restrict__ dw,
             const float* __restrict__ db,
             const u16* __restrict__ a2f,
             float* __restrict__ yout, u16* __restrict__ xdws,
             float* __restrict__ stats) {
    __shared__ u16 xsh[400 * 72];        // 57.6 KB
    __shared__ u16 x3L[OB * OSTR];       // 55.4 KB
    int bid = blockIdx.x;
    int n = bid / 12;
    int o0 = (bid % 12) * 16;
    int tid = threadIdx.x, wid = tid >> 6, lane = tid & 63;
    int lr = lane & 15, lg = lane >> 4;

    // pad slots: v==25 -> 1.0 (bias), 26..35 -> 0
    for (int p = tid; p < OB * 3 * TCH * 11; p += 256) {
        int o = p / 528, r1 = p % 528, s = r1 / 176, r2 = r1 % 176;
        int t = r2 / 11, v = 25 + r2 % 11;
        x3L[o * OSTR + s * SSTR + t * VS + v] = (v == 25) ? (u16)0x3F80 : (u16)0;
    }

    // per-wave GEMM1 B-frags: coltile wid (s=0..2 -> w3, 3 -> down)
    const float* wsrc = (wid < 3) ? (w3 + ((size_t)(wid * O_ + o0 + lr)) * C_)
                                  : (dw + ((size_t)(o0 + lr)) * C_);
    bf16x8 bw[2];
    #pragma unroll
    for (int ks = 0; ks < 2; ++ks) {
        u16x8 tmp;
        #pragma unroll
        for (int j = 0; j < 8; ++j) {
            int c = ks * 32 + (lg << 2) + (j & 3) + ((j >> 2) << 4);
            tmp[j] = f2b(wsrc[c]);
        }
        bw[ks] = __builtin_bit_cast(bf16x8, tmp);
    }
    float dbv = (wid == 3) ? db[o0 + lr] : 0.f;

    float sy1[4] = {0, 0, 0, 0}, sy2[4] = {0, 0, 0, 0};
    float sd1 = 0.f, sd2 = 0.f;
    const u16* xbn = xb + (size_t)n * 6400 * 64;
    const bf16x8* a2v = (const bf16x8*)a2f;

    for (int ch = 0; ch < 16; ++ch) {
        int t0 = ch * TCH;
        __syncthreads();   // protect xsh/x3L from previous chunk's readers
        {
            const u16* src = xbn + (size_t)t0 * 25 * 64;
            for (int p = tid; p < 3200; p += 256) {
                int row = p >> 3, part = p & 7;
                *(float4*)&xsh[row * 72 + part * 8] =
                    *(const float4*)&src[row * 64 + part * 8];
            }
        }
        __syncthreads();
        // GEMM1: D[(t,v), col] ; col = o_local within coltile wid
        for (int rt = 0; rt < 25; ++rt) {
            int base = (rt * 16 + lr) * 72 + (lg << 2);
            u16x4 a0 = *(const u16x4*)&xsh[base];
            u16x4 a1 = *(const u16x4*)&xsh[base + 16];
            u16x4 a2 = *(const u16x4*)&xsh[base + 32];
            u16x4 a3 = *(const u16x4*)&xsh[base + 48];
            f32x4 acc = {0.f, 0.f, 0.f, 0.f};
            acc = mfma16(joinfrag(a0, a1), bw[0], acc);
            acc = mfma16(joinfrag(a2, a3), bw[1], acc);
            if (wid < 3) {
                int ob = lr * OSTR + wid * SSTR;
                #pragma unroll
                for (int reg = 0; reg < 4; ++reg) {
                    int tv = rt * 16 + (lg << 2) + reg;
                    int t = tv / 25, v = tv - t * 25;
                    x3L[ob + t * VS + v] = f2b(acc[reg]);
                }
            } else {
                #pragma unroll
                for (int reg = 0; reg < 4; ++reg) {
                    int tv = rt * 16 + (lg << 2) + reg;
                    int t = tv / 25, v = tv - t * 25;
                    float val = acc[reg] + dbv;
                    xdws[((size_t)(n * O_ + o0 + lr) * T_ + (t0 + t)) * V_ + v] = f2b(val);
                    sd1 += val; sd2 += val * val;
                }
            }
        }
        __syncthreads();
        // GEMM2 per o: y[t,u] = sum_{s,v} X3[t,(s,v)] * A2[(s,v),u]
        for (int oi = 0; oi < 4; ++oi) {
            int ol = wid + oi * 4;
            int o = o0 + ol;
            const bf16x8* bp = a2v + ((size_t)(n * O_ + o)) * 6 * 64 + lane;
            bf16x8 B[6];
            #pragma unroll
            for (int q = 0; q < 6; ++q) B[q] = bp[(size_t)q * 64];
            f32x4 acc0 = {0, 0, 0, 0}, acc1 = {0, 0, 0, 0};
            int abase = ol * OSTR + lr * VS + (lg << 2);
            #pragma unroll
            for (int s = 0; s < 3; ++s) {
                u16x4 lo = *(const u16x4*)&x3L[abase + s * SSTR];
                u16x4 hi = *(const u16x4*)&x3L[abase + s * SSTR + 16];
                bf16x8 A = joinfrag(lo, hi);
                acc0 = mfma16(A, B[s * 2 + 0], acc0);
                acc1 = mfma16(A, B[s * 2 + 1], acc1);
            }
            size_t yb = ((size_t)(n * O_ + o) * T_ + t0 + (lg << 2)) * V_;
            #pragma unroll
            for (int reg = 0; reg < 4; ++reg) {
                float v0 = acc0[reg];
                yout[yb + (size_t)reg * V_ + lr] = v0;
                sy1[oi] += v0; sy2[oi] += v0 * v0;
                if (lr < 9) {
                    float v1 = acc1[reg];
                    yout[yb + (size_t)reg * V_ + 16 + lr] = v1;
                    sy1[oi] += v1; sy2[oi] += v1 * v1;
                }
            }
        }
    }
    // reductions -> global atomics
    #pragma unroll
    for (int oi = 0; oi < 4; ++oi) {
        float v1 = sy1[oi], v2 = sy2[oi];
        #pragma unroll
        for (int m = 1; m < 64; m <<= 1) {
            v1 += __shfl_xor(v1, m);
            v2 += __shfl_xor(v2, m);
        }
        if (lane == 0) {
            atomicAdd(&stats[0 * O_ + o0 + wid + oi * 4], v1);
            atomicAdd(&stats[1 * O_ + o0 + wid + oi * 4], v2);
        }
    }
    if (wid == 3) {
        float v1 = sd1, v2 = sd2;
        v1 += __shfl_xor(v1, 16); v2 += __shfl_xor(v2, 16);
        v1 += __shfl_xor(v1, 32); v2 += __shfl_xor(v2, 32);
        if (lane < 16) {
            atomicAdd(&stats[2 * O_ + o0 + lane], v1);
            atomicAdd(&stats[3 * O_ + o0 + lane], v2);
        }
    }
}

// ---------------- K4: BN coefficients ----------------
__global__ void k4_coef(const float* __restrict__ bn_w, const float* __restrict__ bn_b,
                        const float* __restrict__ dbn_w, const float* __restrict__ dbn_b,
                        const float* __restrict__ stats, float* __restrict__ coef) {
    int o = threadIdx.x;
    if (o >= O_) return;
    float inv = 1.f / (float)(N_ * T_ * V_);
    float mu_y = stats[o] * inv;
    float var_y = stats[O_ + o] * inv - mu_y * mu_y;
    float ay = bn_w[o] * rsqrtf(var_y + 1e-5f);
    float by = bn_b[o] - mu_y * ay;
    float mu_d = stats[2 * O_ + o] * inv;
    float var_d = stats[3 * O_ + o] * inv - mu_d * mu_d;
    float ad = dbn_w[o] * rsqrtf(var_d + 1e-5f);
    float bd = dbn_b[o] - mu_d * ad;
    coef[o] = ay; coef[O_ + o] = by; coef[2 * O_ + o] = ad; coef[3 * O_ + o] = bd;
}

// ---------------- K5: final BN+residual+relu (in-place on d_out) ----------------
__global__ void k5_final(float* __restrict__ out, const u16* __restrict__ xd,
                         const float* __restrict__ cf) {
    size_t total = (size_t)N_ * O_ * TV / 8;
    for (size_t i = blockIdx.x * (size_t)blockDim.x + threadIdx.x; i < total;
         i += (size_t)gridDim.x * blockDim.x) {
        int o = (int)((i / 800) % O_);
        float ay = cf[o], by = cf[O_ + o], ad = cf[2 * O_ + o], bd = cf[3 * O_ + o];
        float4 y0 = ((float4*)out)[2 * i];
        float4 y1 = ((float4*)out)[2 * i + 1];
        u16x8 dv = ((const u16x8*)xd)[i];
        float4 r0, r1;
        r0.x = fmaxf(ay * y0.x + by + ad * b2f(dv[0]) + bd, 0.f);
        r0.y = fmaxf(ay * y0.y + by + ad * b2f(dv[1]) + bd, 0.f);
        r0.z = fmaxf(ay * y0.z + by + ad * b2f(dv[2]) + bd, 0.f);
        r0.w = fmaxf(ay * y0.w + by + ad * b2f(dv[3]) + bd, 0.f);
        r1.x = fmaxf(ay * y1.x + by + ad * b2f(dv[4]) + bd, 0.f);
        r1.y = fmaxf(ay * y1.y + by + ad * b2f(dv[5]) + bd, 0.f);
        r1.z = fmaxf(ay * y1.z + by + ad * b2f(dv[6]) + bd, 0.f);
        r1.w = fmaxf(ay * y1.w + by + ad * b2f(dv[7]) + bd, 0.f);
        ((float4*)out)[2 * i] = r0;
        ((float4*)out)[2 * i + 1] = r1;
    }
}

extern "C" void kernel_launch(void* const* d_in, const int* in_sizes, int n_in,
                              void* d_out, int out_size, void* d_ws, size_t ws_size,
                              hipStream_t stream) {
    const float* x     = (const float*)d_in[0];
    const float* spd   = (const float*)d_in[1];
    const float* A3    = (const float*)d_in[2];
    const float* A6    = (const float*)d_in[3];
    const float* w1    = (const float*)d_in[4];
    const float* b1    = (const float*)d_in[5];
    const float* w2    = (const float*)d_in[6];
    const float* b2    = (const float*)d_in[7];
    const float* w4    = (const float*)d_in[8];
    const float* b4    = (const float*)d_in[9];
    const float* w3    = (const float*)d_in[10];
    const float* b3    = (const float*)d_in[11];
    const float* alpha = (const float*)d_in[12];
    const float* beta  = (const float*)d_in[13];
    const float* gamma = (const float*)d_in[14];
    const float* bn_w  = (const float*)d_in[15];
    const float* bn_b  = (const float*)d_in[16];
    const float* dw    = (const float*)d_in[17];
    const float* db    = (const float*)d_in[18];
    const float* dbn_w = (const float*)d_in[19];
    const float* dbn_b = (const float*)d_in[20];
    float* out = (float*)d_out;
    u16*   wsu = (u16*)d_ws;
    float* wsf = (float*)d_ws;

    u16* a2f  = wsu + WS_A2F_U;
    u16* xb   = wsu + WS_XB_U;
    u16* xd   = wsu + WS_XD_U;
    float* xm    = wsf + WS_XM_F;
    float* stats = wsf + WS_STAT_F;
    float* coef  = wsf + WS_COEF_F;

    hipMemsetAsync(stats, 0, 4 * O_ * sizeof(float), stream);

    k0_xb<<<N_ * 100, 256, 0, stream>>>(x, xb);
    k1_xm<<<N_ * C_, 256, 0, stream>>>(x, xm);
    k2_a2f<<<N_ * S_, 256, 0, stream>>>(spd, A3, A6, w1, b1, w2, b2, w4, b4, b3,
                                        alpha, beta, gamma, a2f, xm);
    k3_main<<<N_ * 12, 256, 0, stream>>>(xb, w3, dw, db, a2f, out, xd, stats);
    k4_coef<<<1, 256, 0, stream>>>(bn_w, bn_b, dbn_w, dbn_b, stats, coef);
    k5_final<<<4096, 256, 0, stream>>>(out, xd, coef);
}

// Round 3
// 472.754 us; speedup vs baseline: 4.3443x; 1.3969x over previous
//
#include <hip/hip_runtime.h>

#define N_ 32
#define C_ 64
#define T_ 256
#define V_ 25
#define O_ 192
#define S_ 3
#define R_ 8
#define VV (V_*V_)      // 625
#define TV (T_*V_)      // 6400

typedef unsigned short u16;
typedef __attribute__((ext_vector_type(4))) u16 u16x4;
typedef __attribute__((ext_vector_type(8))) u16 u16x8;
typedef __attribute__((ext_vector_type(8))) __bf16 bf16x8;
typedef __attribute__((ext_vector_type(4))) float f32x4;

// ---- workspace layout ----
// u16 region:
#define WS_A2F_U 0                                   // N*O*3*2*64*8 = 18,874,368
#define WS_XB_U  (18874368)                          // N*TV*C = 13,107,200
#define WS_XD_U  (18874368 + 13107200)               // N*O*TV = 39,321,600
// float region (after 71,303,168 u16 = 142,606,336 B):
#define WS_XM_F   (35651584)                         // N*C*V = 51,200
#define WS_STAT_F (35651584 + 51200)                 // 4*O
#define WS_COEF_F (35651584 + 51200 + 768)           // 4*O

__device__ __forceinline__ u16 f2b(float f) {
    unsigned u = __builtin_bit_cast(unsigned, f);
    unsigned r = (u + 0x7FFFu + ((u >> 16) & 1u)) >> 16;
    return (u16)r;
}
__device__ __forceinline__ float b2f(u16 u) {
    return __builtin_bit_cast(float, ((unsigned)u) << 16);
}
__device__ __forceinline__ f32x4 mfma16(bf16x8 a, bf16x8 b, f32x4 c) {
    return __builtin_amdgcn_mfma_f32_16x16x32_bf16(a, b, c, 0, 0, 0);
}
__device__ __forceinline__ bf16x8 joinfrag(u16x4 lo, u16x4 hi) {
    return __builtin_bit_cast(bf16x8,
        __builtin_shufflevector(lo, hi, 0, 1, 2, 3, 4, 5, 6, 7));
}

// ---------------- K0: x[n,c,t,v] fp32 -> xb[n,(t,v),c] bf16 ----------------
__global__ void k0_xb(const float* __restrict__ x, u16* __restrict__ xb) {
    __shared__ float tile[64 * 65];
    int bid = blockIdx.x;
    int n = bid / 100, tl = bid % 100;
    int tv0 = tl * 64;
    int tid = threadIdx.x;
    for (int p = tid; p < 1024; p += 256) {
        int c = p >> 4, q = p & 15;
        float4 v = *(const float4*)&x[((size_t)(n * 64 + c)) * 6400 + tv0 + q * 4];
        tile[c * 65 + q * 4 + 0] = v.x;
        tile[c * 65 + q * 4 + 1] = v.y;
        tile[c * 65 + q * 4 + 2] = v.z;
        tile[c * 65 + q * 4 + 3] = v.w;
    }
    __syncthreads();
    for (int p = tid; p < 1024; p += 256) {
        int tvl = p >> 4, cq = p & 15;
        u16x4 w;
        #pragma unroll
        for (int i = 0; i < 4; ++i) w[i] = f2b(tile[(cq * 4 + i) * 65 + tvl]);
        *(u16x4*)&xb[((size_t)n * 6400 + tv0 + tvl) * 64 + cq * 4] = w;
    }
}

// ---------------- K1: xm[n,c,v] = mean_t x[n,c,t,v] ----------------
__global__ void k1_xm(const float* __restrict__ x, float* __restrict__ xm_out) {
    __shared__ float ps[256];
    int nc = blockIdx.x;
    int tid = threadIdx.x;
    const float* xp = x + (size_t)nc * TV;
    float acc = 0.f;
    if (tid < 250) {
        int tg = tid / 25, v = tid % 25;
        for (int j = 0; j < 26; ++j) {
            int t = tg + 10 * j;
            if (t < T_) acc += xp[t * V_ + v];
        }
    }
    ps[tid] = acc;
    __syncthreads();
    if (tid < V_) {
        float s = 0.f;
        for (int tg = 0; tg < 10; ++tg) s += ps[tg * 25 + tid];
        xm_out[(size_t)nc * V_ + tid] = s * (1.f / T_);
    }
}

// ---------------- K2: build A2F (frag-swizzled A_at, bf16) ----------------
// grid: N*S*8 ; each block does 24 o's
__global__ void k2_a2f(const float* __restrict__ spd, const float* __restrict__ A3,
                       const float* __restrict__ A6,
                       const float* __restrict__ w1, const float* __restrict__ b1,
                       const float* __restrict__ w2, const float* __restrict__ b2,
                       const float* __restrict__ w4, const float* __restrict__ b4,
                       const float* __restrict__ b3,
                       const float* __restrict__ alpha, const float* __restrict__ beta,
                       const float* __restrict__ gamma,
                       u16* __restrict__ a2f, const float* __restrict__ xmbuf) {
    __shared__ float xm[C_ * V_];
    __shared__ float x1s[R_ * V_], x2s[R_ * V_];
    __shared__ float dm[R_ * VV];
    __shared__ float a3s[VV], sps[VV], a6s[6 * VV];
    __shared__ float aat[2 * VV];
    __shared__ float rsB[2 * V_];
    __shared__ float w4s[2][R_];
    __shared__ float b4s[2];
    int bid = blockIdx.x;
    int n = bid / 24;
    int rem = bid % 24;
    int s = rem / 8, og = rem % 8;
    int tid = threadIdx.x;
    const float* xmg = xmbuf + (size_t)n * C_ * V_;
    for (int p = tid; p < C_ * V_; p += 256) xm[p] = xmg[p];
    for (int p = tid; p < VV; p += 256) { a3s[p] = A3[s * VV + p]; sps[p] = spd[p]; }
    for (int p = tid; p < 6 * VV; p += 256) a6s[p] = A6[p];
    __syncthreads();
    if (tid < R_ * V_) {
        int r = tid / V_, v = tid % V_;
        float acc1 = b1[s * R_ + r], acc2 = b2[s * R_ + r];
        for (int c = 0; c < C_; ++c) {
            float xv = xm[c * V_ + v];
            acc1 += xv * w1[(s * R_ + r) * C_ + c];
            acc2 += xv * w2[(s * R_ + r) * C_ + c];
        }
        x1s[tid] = acc1; x2s[tid] = acc2;
    }
    __syncthreads();
    for (int p = tid; p < R_ * VV; p += 256) {
        int r = p / VV, uv = p % VV, u = uv / V_, v = uv % V_;
        dm[p] = tanhf(x1s[r * V_ + u] - x2s[r * V_ + v]);
    }
    __syncthreads();
    float al = alpha[0], be = beta[0], ga = gamma[0];
    for (int op = 0; op < 12; ++op) {
        int o0 = og * 24 + op * 2;
        if (tid < 16) w4s[tid >> 3][tid & 7] =
            w4[((size_t)(s * O_ + o0 + (tid >> 3))) * R_ + (tid & 7)];
        if (tid < 2) b4s[tid] = b4[s * O_ + o0 + tid];
        __syncthreads();
        for (int p = tid; p < 2 * VV; p += 256) {
            int oo = p / VV, pp = p % VV;
            float acc = b4s[oo];
            #pragma unroll
            for (int r = 0; r < R_; ++r) acc += dm[r * VV + pp] * w4s[oo][r];
            int o = o0 + oo;
            aat[p] = al * acc + a3s[pp] + be * a6s[(o % 6) * VV + pp] + ga * sps[pp];
        }
        __syncthreads();
        if (tid < 2 * V_) {
            int oo = tid / V_, u = tid % V_;
            float rs = 0.f;
            for (int v = 0; v < V_; ++v) rs += aat[oo * VV + u * V_ + v];
            rsB[tid] = b3[s * O_ + o0 + oo] * rs;
        }
        __syncthreads();
        {
            int oo = tid >> 7, l2 = tid & 127, cu = l2 >> 6, l = l2 & 63;
            int u = cu * 16 + (l & 15);
            u16x8 w;
            #pragma unroll
            for (int j = 0; j < 8; ++j) {
                int v = ((j >> 2) << 4) + ((l >> 4) << 2) + (j & 3);
                float val = 0.f;
                if (u < V_) {
                    if (v < V_) val = aat[oo * VV + u * V_ + v];
                    else if (v == V_) val = rsB[oo * V_ + u];
                }
                w[j] = f2b(val);
            }
            size_t idx = ((((size_t)(n * O_ + o0 + oo)) * S_ + s) * 2 + cu) * 64 + l;
            ((u16x8*)a2f)[idx] = w;
        }
        __syncthreads();
    }
}

// ---------------- K3: fused MFMA GEMM1+GEMM2 + down + stats ----------------
// grid: N * 12 o-tiles * 4 t-quarters; each block does 4 chunks of 16 t.
// LDS: x3L only (52.3 KB) -> 3 blocks/CU, 12 waves/CU.
#define TCH 16
#define OB 16
#define VS 34
#define SSTR (TCH*VS)        // 544
#define OSTR (3*SSTR + 2)    // 1634 (odd*2 -> 16 lanes hit 16 distinct banks)

__global__ __launch_bounds__(256, 3)
void k3_main(const u16* __restrict__ xb,
             const float* __restrict__ w3, const float* __restrict__ dw,
             const float* __restrict__ db,
             const u16* __restrict__ a2f,
             float* __restrict__ yout, u16* __restrict__ xdws,
             float* __restrict__ stats) {
    __shared__ u16 x3L[OB * OSTR];       // 52,288 B
    int bid = blockIdx.x;
    int n = bid / 48;
    int rem = bid % 48;
    int o0 = (rem / 4) * 16;
    int tq = rem % 4;
    int tid = threadIdx.x, wid = tid >> 6, lane = tid & 63;
    int lr = lane & 15, lg = lane >> 4;

    // pad slots: v==25 -> 1.0 (bias), 26..33 -> 0 (written once; GEMM1 only writes v<25)
    for (int p = tid; p < OB * 3 * TCH * 9; p += 256) {
        int ol = p / 432, r1 = p % 432, s = r1 / 144, r2 = r1 % 144;
        int t = r2 / 9, v = 25 + r2 % 9;
        x3L[ol * OSTR + s * SSTR + t * VS + v] = (v == 25) ? (u16)0x3F80 : (u16)0;
    }

    // per-wave GEMM1 B-frags: coltile wid (s=0..2 -> w3, 3 -> down)
    const float* wsrc = (wid < 3) ? (w3 + ((size_t)(wid * O_ + o0 + lr)) * C_)
                                  : (dw + ((size_t)(o0 + lr)) * C_);
    bf16x8 bw[2];
    #pragma unroll
    for (int ks = 0; ks < 2; ++ks) {
        u16x8 tmp;
        #pragma unroll
        for (int j = 0; j < 8; ++j) {
            int c = ks * 32 + (lg << 2) + (j & 3) + ((j >> 2) << 4);
            tmp[j] = f2b(wsrc[c]);
        }
        bw[ks] = __builtin_bit_cast(bf16x8, tmp);
    }
    float dbv = (wid == 3) ? db[o0 + lr] : 0.f;

    float sy1[4] = {0, 0, 0, 0}, sy2[4] = {0, 0, 0, 0};
    float sd1 = 0.f, sd2 = 0.f;
    const u16* xbn = xb + (size_t)n * 6400 * 64;
    const bf16x8* a2v = (const bf16x8*)a2f;

    for (int ch = 0; ch < 4; ++ch) {
        int t0 = (tq * 4 + ch) * TCH;
        __syncthreads();   // protect x3L from previous chunk's readers
        // GEMM1: A-frags straight from global (L1/L2-resident xb)
        const u16* xrow = xbn + (size_t)t0 * 25 * 64;
        for (int rt = 0; rt < 25; ++rt) {
            int rb = (rt * 16 + lr) * 64 + (lg << 2);
            u16x4 a0 = *(const u16x4*)&xrow[rb];
            u16x4 a1 = *(const u16x4*)&xrow[rb + 16];
            u16x4 a2 = *(const u16x4*)&xrow[rb + 32];
            u16x4 a3 = *(const u16x4*)&xrow[rb + 48];
            f32x4 acc = {0.f, 0.f, 0.f, 0.f};
            acc = mfma16(joinfrag(a0, a1), bw[0], acc);
            acc = mfma16(joinfrag(a2, a3), bw[1], acc);
            if (wid < 3) {
                int ob = lr * OSTR + wid * SSTR;
                #pragma unroll
                for (int reg = 0; reg < 4; ++reg) {
                    int tv = rt * 16 + (lg << 2) + reg;
                    int t = tv / 25, v = tv - t * 25;
                    x3L[ob + t * VS + v] = f2b(acc[reg]);
                }
            } else {
                #pragma unroll
                for (int reg = 0; reg < 4; ++reg) {
                    int tv = rt * 16 + (lg << 2) + reg;
                    int t = tv / 25, v = tv - t * 25;
                    float val = acc[reg] + dbv;
                    xdws[((size_t)(n * O_ + o0 + lr) * T_ + (t0 + t)) * V_ + v] = f2b(val);
                    sd1 += val; sd2 += val * val;
                }
            }
        }
        __syncthreads();
        // GEMM2 per o: y[t,u] = sum_{s,v} X3[t,(s,v)] * A2[(s,v),u]
        for (int oi = 0; oi < 4; ++oi) {
            int ol = wid + oi * 4;
            int o = o0 + ol;
            const bf16x8* bp = a2v + ((size_t)(n * O_ + o)) * 6 * 64 + lane;
            bf16x8 B[6];
            #pragma unroll
            for (int q = 0; q < 6; ++q) B[q] = bp[(size_t)q * 64];
            f32x4 acc0 = {0, 0, 0, 0}, acc1 = {0, 0, 0, 0};
            int abase = ol * OSTR + lr * VS + (lg << 2);
            #pragma unroll
            for (int s = 0; s < 3; ++s) {
                u16x4 lo = *(const u16x4*)&x3L[abase + s * SSTR];
                u16x4 hi = *(const u16x4*)&x3L[abase + s * SSTR + 16];
                bf16x8 A = joinfrag(lo, hi);
                acc0 = mfma16(A, B[s * 2 + 0], acc0);
                acc1 = mfma16(A, B[s * 2 + 1], acc1);
            }
            size_t yb = ((size_t)(n * O_ + o) * T_ + t0 + (lg << 2)) * V_;
            #pragma unroll
            for (int reg = 0; reg < 4; ++reg) {
                float v0 = acc0[reg];
                yout[yb + (size_t)reg * V_ + lr] = v0;
                sy1[oi] += v0; sy2[oi] += v0 * v0;
                if (lr < 9) {
                    float v1 = acc1[reg];
                    yout[yb + (size_t)reg * V_ + 16 + lr] = v1;
                    sy1[oi] += v1; sy2[oi] += v1 * v1;
                }
            }
        }
    }
    // reductions -> global atomics
    #pragma unroll
    for (int oi = 0; oi < 4; ++oi) {
        float v1 = sy1[oi], v2 = sy2[oi];
        #pragma unroll
        for (int m = 1; m < 64; m <<= 1) {
            v1 += __shfl_xor(v1, m);
            v2 += __shfl_xor(v2, m);
        }
        if (lane == 0) {
            atomicAdd(&stats[0 * O_ + o0 + wid + oi * 4], v1);
            atomicAdd(&stats[1 * O_ + o0 + wid + oi * 4], v2);
        }
    }
    if (wid == 3) {
        float v1 = sd1, v2 = sd2;
        v1 += __shfl_xor(v1, 16); v2 += __shfl_xor(v2, 16);
        v1 += __shfl_xor(v1, 32); v2 += __shfl_xor(v2, 32);
        if (lane < 16) {
            atomicAdd(&stats[2 * O_ + o0 + lane], v1);
            atomicAdd(&stats[3 * O_ + o0 + lane], v2);
        }
    }
}

// ---------------- K4: BN coefficients ----------------
__global__ void k4_coef(const float* __restrict__ bn_w, const float* __restrict__ bn_b,
                        const float* __restrict__ dbn_w, const float* __restrict__ dbn_b,
                        const float* __restrict__ stats, float* __restrict__ coef) {
    int o = threadIdx.x;
    if (o >= O_) return;
    float inv = 1.f / (float)(N_ * T_ * V_);
    float mu_y = stats[o] * inv;
    float var_y = stats[O_ + o] * inv - mu_y * mu_y;
    float ay = bn_w[o] * rsqrtf(var_y + 1e-5f);
    float by = bn_b[o] - mu_y * ay;
    float mu_d = stats[2 * O_ + o] * inv;
    float var_d = stats[3 * O_ + o] * inv - mu_d * mu_d;
    float ad = dbn_w[o] * rsqrtf(var_d + 1e-5f);
    float bd = dbn_b[o] - mu_d * ad;
    coef[o] = ay; coef[O_ + o] = by; coef[2 * O_ + o] = ad; coef[3 * O_ + o] = bd;
}

// ---------------- K5: final BN+residual+relu (in-place on d_out) ----------------
__global__ void k5_final(float* __restrict__ out, const u16* __restrict__ xd,
                         const float* __restrict__ cf) {
    size_t total = (size_t)N_ * O_ * TV / 8;
    for (size_t i = blockIdx.x * (size_t)blockDim.x + threadIdx.x; i < total;
         i += (size_t)gridDim.x * blockDim.x) {
        int o = (int)((i / 800) % O_);
        float ay = cf[o], by = cf[O_ + o], ad = cf[2 * O_ + o], bd = cf[3 * O_ + o];
        float4 y0 = ((float4*)out)[2 * i];
        float4 y1 = ((float4*)out)[2 * i + 1];
        u16x8 dv = ((const u16x8*)xd)[i];
        float4 r0, r1;
        r0.x = fmaxf(ay * y0.x + by + ad * b2f(dv[0]) + bd, 0.f);
        r0.y = fmaxf(ay * y0.y + by + ad * b2f(dv[1]) + bd, 0.f);
        r0.z = fmaxf(ay * y0.z + by + ad * b2f(dv[2]) + bd, 0.f);
        r0.w = fmaxf(ay * y0.w + by + ad * b2f(dv[3]) + bd, 0.f);
        r1.x = fmaxf(ay * y1.x + by + ad * b2f(dv[4]) + bd, 0.f);
        r1.y = fmaxf(ay * y1.y + by + ad * b2f(dv[5]) + bd, 0.f);
        r1.z = fmaxf(ay * y1.z + by + ad * b2f(dv[6]) + bd, 0.f);
        r1.w = fmaxf(ay * y1.w + by + ad * b2f(dv[7]) + bd, 0.f);
        ((float4*)out)[2 * i] = r0;
        ((float4*)out)[2 * i + 1] = r1;
    }
}

extern "C" void kernel_launch(void* const* d_in, const int* in_sizes, int n_in,
                              void* d_out, int out_size, void* d_ws, size_t ws_size,
                              hipStream_t stream) {
    const float* x     = (const float*)d_in[0];
    const float* spd   = (const float*)d_in[1];
    const float* A3    = (const float*)d_in[2];
    const float* A6    = (const float*)d_in[3];
    const float* w1    = (const float*)d_in[4];
    const float* b1    = (const float*)d_in[5];
    const float* w2    = (const float*)d_in[6];
    const float* b2    = (const float*)d_in[7];
    const float* w4    = (const float*)d_in[8];
    const float* b4    = (const float*)d_in[9];
    const float* w3    = (const float*)d_in[10];
    const float* b3    = (const float*)d_in[11];
    const float* alpha = (const float*)d_in[12];
    const float* beta  = (const float*)d_in[13];
    const float* gamma = (const float*)d_in[14];
    const float* bn_w  = (const float*)d_in[15];
    const float* bn_b  = (const float*)d_in[16];
    const float* dw    = (const float*)d_in[17];
    const float* db    = (const float*)d_in[18];
    const float* dbn_w = (const float*)d_in[19];
    const float* dbn_b = (const float*)d_in[20];
    float* out = (float*)d_out;
    u16*   wsu = (u16*)d_ws;
    float* wsf = (float*)d_ws;

    u16* a2f  = wsu + WS_A2F_U;
    u16* xb   = wsu + WS_XB_U;
    u16* xd   = wsu + WS_XD_U;
    float* xm    = wsf + WS_XM_F;
    float* stats = wsf + WS_STAT_F;
    float* coef  = wsf + WS_COEF_F;

    hipMemsetAsync(stats, 0, 4 * O_ * sizeof(float), stream);

    k0_xb<<<N_ * 100, 256, 0, stream>>>(x, xb);
    k1_xm<<<N_ * C_, 256, 0, stream>>>(x, xm);
    k2_a2f<<<N_ * S_ * 8, 256, 0, stream>>>(spd, A3, A6, w1, b1, w2, b2, w4, b4, b3,
                                            alpha, beta, gamma, a2f, xm);
    k3_main<<<N_ * 48, 256, 0, stream>>>(xb, w3, dw, db, a2f, out, xd, stats);
    k4_coef<<<1, 256, 0, stream>>>(bn_w, bn_b, dbn_w, dbn_b, stats, coef);
    k5_final<<<4096, 256, 0, stream>>>(out, xd, coef);
}

// Round 4
// 459.326 us; speedup vs baseline: 4.4713x; 1.0292x over previous
//
#include <hip/hip_runtime.h>

#define N_ 32
#define C_ 64
#define T_ 256
#define V_ 25
#define O_ 192
#define S_ 3
#define R_ 8
#define VV (V_*V_)      // 625
#define TV (T_*V_)      // 6400

typedef unsigned short u16;
typedef __attribute__((ext_vector_type(4))) u16 u16x4;
typedef __attribute__((ext_vector_type(8))) u16 u16x8;
typedef __attribute__((ext_vector_type(8))) __bf16 bf16x8;
typedef __attribute__((ext_vector_type(4))) float f32x4;

// ---- workspace layout ----
// u16 region:
#define WS_A2F_U 0                                   // N*O*3*2*64*8 = 18,874,368
#define WS_XB_U  (18874368)                          // N*TV*C = 13,107,200
#define WS_XD_U  (18874368 + 13107200)               // N*O*TV = 39,321,600
// float region (after 71,303,168 u16 = 142,606,336 B):
#define WS_XM_F   (35651584)                         // N*C*V = 51,200
#define WS_STAT_F (35651584 + 51200)                 // 4*O
#define WS_COEF_F (35651584 + 51200 + 768)           // 4*O

__device__ __forceinline__ u16 f2b(float f) {
    unsigned u = __builtin_bit_cast(unsigned, f);
    unsigned r = (u + 0x7FFFu + ((u >> 16) & 1u)) >> 16;
    return (u16)r;
}
__device__ __forceinline__ float b2f(u16 u) {
    return __builtin_bit_cast(float, ((unsigned)u) << 16);
}
__device__ __forceinline__ f32x4 mfma16(bf16x8 a, bf16x8 b, f32x4 c) {
    return __builtin_amdgcn_mfma_f32_16x16x32_bf16(a, b, c, 0, 0, 0);
}
__device__ __forceinline__ bf16x8 joinfrag(u16x4 lo, u16x4 hi) {
    return __builtin_bit_cast(bf16x8,
        __builtin_shufflevector(lo, hi, 0, 1, 2, 3, 4, 5, 6, 7));
}

// ---------------- K0: x[n,c,t,v] fp32 -> xb[n,(t,v),c] bf16 ----------------
__global__ void k0_xb(const float* __restrict__ x, u16* __restrict__ xb) {
    __shared__ float tile[64 * 65];
    int bid = blockIdx.x;
    int n = bid / 100, tl = bid % 100;
    int tv0 = tl * 64;
    int tid = threadIdx.x;
    for (int p = tid; p < 1024; p += 256) {
        int c = p >> 4, q = p & 15;
        float4 v = *(const float4*)&x[((size_t)(n * 64 + c)) * 6400 + tv0 + q * 4];
        tile[c * 65 + q * 4 + 0] = v.x;
        tile[c * 65 + q * 4 + 1] = v.y;
        tile[c * 65 + q * 4 + 2] = v.z;
        tile[c * 65 + q * 4 + 3] = v.w;
    }
    __syncthreads();
    for (int p = tid; p < 1024; p += 256) {
        int tvl = p >> 4, cq = p & 15;
        u16x4 w;
        #pragma unroll
        for (int i = 0; i < 4; ++i) w[i] = f2b(tile[(cq * 4 + i) * 65 + tvl]);
        *(u16x4*)&xb[((size_t)n * 6400 + tv0 + tvl) * 64 + cq * 4] = w;
    }
}

// ---------------- K1: xm[n,c,v] = mean_t x[n,c,t,v] ----------------
__global__ void k1_xm(const float* __restrict__ x, float* __restrict__ xm_out) {
    __shared__ float ps[256];
    int nc = blockIdx.x;
    int tid = threadIdx.x;
    const float* xp = x + (size_t)nc * TV;
    float acc = 0.f;
    if (tid < 250) {
        int tg = tid / 25, v = tid % 25;
        for (int j = 0; j < 26; ++j) {
            int t = tg + 10 * j;
            if (t < T_) acc += xp[t * V_ + v];
        }
    }
    ps[tid] = acc;
    __syncthreads();
    if (tid < V_) {
        float s = 0.f;
        for (int tg = 0; tg < 10; ++tg) s += ps[tg * 25 + tid];
        xm_out[(size_t)nc * V_ + tid] = s * (1.f / T_);
    }
}

// ---------------- K2: build A2F (frag-swizzled A_at, bf16) ----------------
// grid: N*S*8 ; each block does 24 o's
__global__ void k2_a2f(const float* __restrict__ spd, const float* __restrict__ A3,
                       const float* __restrict__ A6,
                       const float* __restrict__ w1, const float* __restrict__ b1,
                       const float* __restrict__ w2, const float* __restrict__ b2,
                       const float* __restrict__ w4, const float* __restrict__ b4,
                       const float* __restrict__ b3,
                       const float* __restrict__ alpha, const float* __restrict__ beta,
                       const float* __restrict__ gamma,
                       u16* __restrict__ a2f, const float* __restrict__ xmbuf) {
    __shared__ float xm[C_ * V_];
    __shared__ float x1s[R_ * V_], x2s[R_ * V_];
    __shared__ float dm[R_ * VV];
    __shared__ float a3s[VV], sps[VV], a6s[6 * VV];
    __shared__ float aat[2 * VV];
    __shared__ float rsB[2 * V_];
    __shared__ float w4s[2][R_];
    __shared__ float b4s[2];
    int bid = blockIdx.x;
    int n = bid / 24;
    int rem = bid % 24;
    int s = rem / 8, og = rem % 8;
    int tid = threadIdx.x;
    const float* xmg = xmbuf + (size_t)n * C_ * V_;
    for (int p = tid; p < C_ * V_; p += 256) xm[p] = xmg[p];
    for (int p = tid; p < VV; p += 256) { a3s[p] = A3[s * VV + p]; sps[p] = spd[p]; }
    for (int p = tid; p < 6 * VV; p += 256) a6s[p] = A6[p];
    __syncthreads();
    if (tid < R_ * V_) {
        int r = tid / V_, v = tid % V_;
        float acc1 = b1[s * R_ + r], acc2 = b2[s * R_ + r];
        for (int c = 0; c < C_; ++c) {
            float xv = xm[c * V_ + v];
            acc1 += xv * w1[(s * R_ + r) * C_ + c];
            acc2 += xv * w2[(s * R_ + r) * C_ + c];
        }
        x1s[tid] = acc1; x2s[tid] = acc2;
    }
    __syncthreads();
    for (int p = tid; p < R_ * VV; p += 256) {
        int r = p / VV, uv = p % VV, u = uv / V_, v = uv % V_;
        dm[p] = tanhf(x1s[r * V_ + u] - x2s[r * V_ + v]);
    }
    __syncthreads();
    float al = alpha[0], be = beta[0], ga = gamma[0];
    for (int op = 0; op < 12; ++op) {
        int o0 = og * 24 + op * 2;
        if (tid < 16) w4s[tid >> 3][tid & 7] =
            w4[((size_t)(s * O_ + o0 + (tid >> 3))) * R_ + (tid & 7)];
        if (tid < 2) b4s[tid] = b4[s * O_ + o0 + tid];
        __syncthreads();
        for (int p = tid; p < 2 * VV; p += 256) {
            int oo = p / VV, pp = p % VV;
            float acc = b4s[oo];
            #pragma unroll
            for (int r = 0; r < R_; ++r) acc += dm[r * VV + pp] * w4s[oo][r];
            int o = o0 + oo;
            aat[p] = al * acc + a3s[pp] + be * a6s[(o % 6) * VV + pp] + ga * sps[pp];
        }
        __syncthreads();
        if (tid < 2 * V_) {
            int oo = tid / V_, u = tid % V_;
            float rs = 0.f;
            for (int v = 0; v < V_; ++v) rs += aat[oo * VV + u * V_ + v];
            rsB[tid] = b3[s * O_ + o0 + oo] * rs;
        }
        __syncthreads();
        {
            int oo = tid >> 7, l2 = tid & 127, cu = l2 >> 6, l = l2 & 63;
            int u = cu * 16 + (l & 15);
            u16x8 w;
            #pragma unroll
            for (int j = 0; j < 8; ++j) {
                int v = ((j >> 2) << 4) + ((l >> 4) << 2) + (j & 3);
                float val = 0.f;
                if (u < V_) {
                    if (v < V_) val = aat[oo * VV + u * V_ + v];
                    else if (v == V_) val = rsB[oo * V_ + u];
                }
                w[j] = f2b(val);
            }
            size_t idx = ((((size_t)(n * O_ + o0 + oo)) * S_ + s) * 2 + cu) * 64 + l;
            ((u16x8*)a2f)[idx] = w;
        }
        __syncthreads();
    }
}

// ---------------- K3: fused MFMA GEMM1+GEMM2 + down + stats ----------------
// grid: N*24 = 768 blocks (exactly 3/CU). OB=8 o's per block, all 256 t.
// Double-buffered x3L: 1 barrier/chunk. GEMM2 B hoisted in regs. XCD swizzle.
#define TCH 16
#define OB 8
#define VS 34
#define SSTR (TCH*VS)        // 544  (word-step 16 mod 32)
#define OSTR (3*SSTR + 2)    // 1634 (word-step 17 mod 32)

__global__ __launch_bounds__(256, 3)
void k3_main(const u16* __restrict__ xb,
             const float* __restrict__ w3, const float* __restrict__ dw,
             const float* __restrict__ db,
             const u16* __restrict__ a2f,
             float* __restrict__ yout, u16* __restrict__ xdws,
             float* __restrict__ stats) {
    __shared__ u16 x3L[2][OB * OSTR];   // 2 x 26,144 B = 52,288 B
    int orig = blockIdx.x;
    int bid = (orig & 7) * 96 + (orig >> 3);   // bijective: same-n blocks -> same XCD
    int n = bid / 24;
    int o0 = (bid % 24) * OB;
    int tid = threadIdx.x, wid = tid >> 6, lane = tid & 63;
    int lr = lane & 15, lg = lane >> 4;
    int colt = wid & 1;
    int rt0 = (wid >> 1) ? 13 : 0, rt1 = (wid >> 1) ? 25 : 13;

    // pad slots (v=25 -> 1.0 bias row, 26..33 -> 0), both buffers, written once
    for (int b = 0; b < 2; ++b)
        for (int p = tid; p < OB * 3 * TCH * 9; p += 256) {
            int ol = p / 432, r1 = p % 432, s = r1 / 144, r2 = r1 % 144;
            int t = r2 / 9, v = 25 + r2 % 9;
            x3L[b][ol * OSTR + s * SSTR + t * VS + v] = (v == 25) ? (u16)0x3F80 : (u16)0;
        }

    // GEMM1 B-frags: colt0 cols = (s0,o0..7)|(s1,o0..7); colt1 = (s2,o0..7)|(down,o0..7)
    const float* wsrc = (colt == 0)
        ? w3 + ((size_t)((lr >> 3) * O_ + o0 + (lr & 7))) * C_
        : ((lr < 8) ? w3 + ((size_t)(2 * O_ + o0 + lr)) * C_
                    : dw + ((size_t)(o0 + lr - 8)) * C_);
    bf16x8 bw[2];
    #pragma unroll
    for (int ks = 0; ks < 2; ++ks) {
        u16x8 tmp;
        #pragma unroll
        for (int j = 0; j < 8; ++j) {
            int c = ks * 32 + (lg << 2) + (j & 3) + ((j >> 2) << 4);
            tmp[j] = f2b(wsrc[c]);
        }
        bw[ks] = __builtin_bit_cast(bf16x8, tmp);
    }
    float dbv = (colt == 1 && lr >= 8) ? db[o0 + lr - 8] : 0.f;

    // hoisted GEMM2 B-frags: wave covers o = o0 + wid*2 + {0,1}
    const bf16x8* a2v = (const bf16x8*)a2f;
    bf16x8 Bh[2][6];
    #pragma unroll
    for (int oi = 0; oi < 2; ++oi) {
        const bf16x8* bp = a2v + ((size_t)(n * O_ + o0 + (wid << 1) + oi)) * 6 * 64 + lane;
        #pragma unroll
        for (int q = 0; q < 6; ++q) Bh[oi][q] = bp[(size_t)q * 64];
    }

    float sy1[2] = {0, 0}, sy2[2] = {0, 0};
    float sd1 = 0.f, sd2 = 0.f;
    const u16* xbn = xb + (size_t)n * 6400 * 64;

    for (int ch = 0; ch < 16; ++ch) {
        int t0 = ch * TCH;
        u16* buf = x3L[ch & 1];
        const u16* xrow = xbn + (size_t)t0 * 25 * 64;
        // GEMM1: A from global (L2-local via XCD swizzle)
        for (int rt = rt0; rt < rt1; ++rt) {
            int rb = (rt * 16 + lr) * 64 + (lg << 2);
            u16x4 a0 = *(const u16x4*)&xrow[rb];
            u16x4 a1 = *(const u16x4*)&xrow[rb + 16];
            u16x4 a2 = *(const u16x4*)&xrow[rb + 32];
            u16x4 a3 = *(const u16x4*)&xrow[rb + 48];
            f32x4 acc = {0.f, 0.f, 0.f, 0.f};
            acc = mfma16(joinfrag(a0, a1), bw[0], acc);
            acc = mfma16(joinfrag(a2, a3), bw[1], acc);
            int tvb = rt * 16 + (lg << 2);
            int t = tvb / 25, v = tvb - t * 25;
            if (colt == 0 || lr < 8) {
                int base = (colt == 0) ? ((lr & 7) * OSTR + (lr >> 3) * SSTR)
                                       : (lr * OSTR + 2 * SSTR);
                #pragma unroll
                for (int reg = 0; reg < 4; ++reg) {
                    int vv = v + reg, tt = t;
                    if (vv >= 25) { vv -= 25; ++tt; }
                    buf[base + tt * VS + vv] = f2b(acc[reg]);
                }
            } else {
                size_t xdb = ((size_t)(n * O_ + o0 + lr - 8)) * TV + (size_t)t0 * V_;
                #pragma unroll
                for (int reg = 0; reg < 4; ++reg) {
                    int vv = v + reg, tt = t;
                    if (vv >= 25) { vv -= 25; ++tt; }
                    float val = acc[reg] + dbv;
                    xdws[xdb + tt * V_ + vv] = f2b(val);
                    sd1 += val; sd2 += val * val;
                }
            }
        }
        __syncthreads();   // single barrier: double-buffer covers the other hazard
        // GEMM2: y[t,u] = sum_{s,v} X3[t,(s,v)] * A2[(s,v),u]
        #pragma unroll
        for (int oi = 0; oi < 2; ++oi) {
            int ol = (wid << 1) + oi;
            int o = o0 + ol;
            f32x4 acc0 = {0, 0, 0, 0}, acc1 = {0, 0, 0, 0};
            int abase = ol * OSTR + lr * VS + (lg << 2);
            #pragma unroll
            for (int s = 0; s < 3; ++s) {
                u16x4 lo = *(const u16x4*)&buf[abase + s * SSTR];
                u16x4 hi = *(const u16x4*)&buf[abase + s * SSTR + 16];
                bf16x8 A = joinfrag(lo, hi);
                acc0 = mfma16(A, Bh[oi][s * 2 + 0], acc0);
                acc1 = mfma16(A, Bh[oi][s * 2 + 1], acc1);
            }
            size_t yb = ((size_t)(n * O_ + o) * T_ + t0 + (lg << 2)) * V_;
            #pragma unroll
            for (int reg = 0; reg < 4; ++reg) {
                float v0 = acc0[reg];
                yout[yb + (size_t)reg * V_ + lr] = v0;
                sy1[oi] += v0; sy2[oi] += v0 * v0;
                if (lr < 9) {
                    float v1 = acc1[reg];
                    yout[yb + (size_t)reg * V_ + 16 + lr] = v1;
                    sy1[oi] += v1; sy2[oi] += v1 * v1;
                }
            }
        }
    }
    // stats -> global atomics
    #pragma unroll
    for (int oi = 0; oi < 2; ++oi) {
        float v1 = sy1[oi], v2 = sy2[oi];
        #pragma unroll
        for (int m = 1; m < 64; m <<= 1) {
            v1 += __shfl_xor(v1, m);
            v2 += __shfl_xor(v2, m);
        }
        if (lane == 0) {
            atomicAdd(&stats[0 * O_ + o0 + (wid << 1) + oi], v1);
            atomicAdd(&stats[1 * O_ + o0 + (wid << 1) + oi], v2);
        }
    }
    if (colt == 1) {
        float v1 = sd1, v2 = sd2;
        v1 += __shfl_xor(v1, 16); v2 += __shfl_xor(v2, 16);
        v1 += __shfl_xor(v1, 32); v2 += __shfl_xor(v2, 32);
        if (lane >= 8 && lane < 16) {
            atomicAdd(&stats[2 * O_ + o0 + lane - 8], v1);
            atomicAdd(&stats[3 * O_ + o0 + lane - 8], v2);
        }
    }
}

// ---------------- K4: BN coefficients ----------------
__global__ void k4_coef(const float* __restrict__ bn_w, const float* __restrict__ bn_b,
                        const float* __restrict__ dbn_w, const float* __restrict__ dbn_b,
                        const float* __restrict__ stats, float* __restrict__ coef) {
    int o = threadIdx.x;
    if (o >= O_) return;
    float inv = 1.f / (float)(N_ * T_ * V_);
    float mu_y = stats[o] * inv;
    float var_y = stats[O_ + o] * inv - mu_y * mu_y;
    float ay = bn_w[o] * rsqrtf(var_y + 1e-5f);
    float by = bn_b[o] - mu_y * ay;
    float mu_d = stats[2 * O_ + o] * inv;
    float var_d = stats[3 * O_ + o] * inv - mu_d * mu_d;
    float ad = dbn_w[o] * rsqrtf(var_d + 1e-5f);
    float bd = dbn_b[o] - mu_d * ad;
    coef[o] = ay; coef[O_ + o] = by; coef[2 * O_ + o] = ad; coef[3 * O_ + o] = bd;
}

// ---------------- K5: final BN+residual+relu (in-place on d_out) ----------------
__global__ void k5_final(float* __restrict__ out, const u16* __restrict__ xd,
                         const float* __restrict__ cf) {
    size_t total = (size_t)N_ * O_ * TV / 8;
    for (size_t i = blockIdx.x * (size_t)blockDim.x + threadIdx.x; i < total;
         i += (size_t)gridDim.x * blockDim.x) {
        int o = (int)((i / 800) % O_);
        float ay = cf[o], by = cf[O_ + o], ad = cf[2 * O_ + o], bd = cf[3 * O_ + o];
        float4 y0 = ((float4*)out)[2 * i];
        float4 y1 = ((float4*)out)[2 * i + 1];
        u16x8 dv = ((const u16x8*)xd)[i];
        float4 r0, r1;
        r0.x = fmaxf(ay * y0.x + by + ad * b2f(dv[0]) + bd, 0.f);
        r0.y = fmaxf(ay * y0.y + by + ad * b2f(dv[1]) + bd, 0.f);
        r0.z = fmaxf(ay * y0.z + by + ad * b2f(dv[2]) + bd, 0.f);
        r0.w = fmaxf(ay * y0.w + by + ad * b2f(dv[3]) + bd, 0.f);
        r1.x = fmaxf(ay * y1.x + by + ad * b2f(dv[4]) + bd, 0.f);
        r1.y = fmaxf(ay * y1.y + by + ad * b2f(dv[5]) + bd, 0.f);
        r1.z = fmaxf(ay * y1.z + by + ad * b2f(dv[6]) + bd, 0.f);
        r1.w = fmaxf(ay * y1.w + by + ad * b2f(dv[7]) + bd, 0.f);
        ((float4*)out)[2 * i] = r0;
        ((float4*)out)[2 * i + 1] = r1;
    }
}

extern "C" void kernel_launch(void* const* d_in, const int* in_sizes, int n_in,
                              void* d_out, int out_size, void* d_ws, size_t ws_size,
                              hipStream_t stream) {
    const float* x     = (const float*)d_in[0];
    const float* spd   = (const float*)d_in[1];
    const float* A3    = (const float*)d_in[2];
    const float* A6    = (const float*)d_in[3];
    const float* w1    = (const float*)d_in[4];
    const float* b1    = (const float*)d_in[5];
    const float* w2    = (const float*)d_in[6];
    const float* b2    = (const float*)d_in[7];
    const float* w4    = (const float*)d_in[8];
    const float* b4    = (const float*)d_in[9];
    const float* w3    = (const float*)d_in[10];
    const float* b3    = (const float*)d_in[11];
    const float* alpha = (const float*)d_in[12];
    const float* beta  = (const float*)d_in[13];
    const float* gamma = (const float*)d_in[14];
    const float* bn_w  = (const float*)d_in[15];
    const float* bn_b  = (const float*)d_in[16];
    const float* dw    = (const float*)d_in[17];
    const float* db    = (const float*)d_in[18];
    const float* dbn_w = (const float*)d_in[19];
    const float* dbn_b = (const float*)d_in[20];
    float* out = (float*)d_out;
    u16*   wsu = (u16*)d_ws;
    float* wsf = (float*)d_ws;

    u16* a2f  = wsu + WS_A2F_U;
    u16* xb   = wsu + WS_XB_U;
    u16* xd   = wsu + WS_XD_U;
    float* xm    = wsf + WS_XM_F;
    float* stats = wsf + WS_STAT_F;
    float* coef  = wsf + WS_COEF_F;

    hipMemsetAsync(stats, 0, 4 * O_ * sizeof(float), stream);

    k0_xb<<<N_ * 100, 256, 0, stream>>>(x, xb);
    k1_xm<<<N_ * C_, 256, 0, stream>>>(x, xm);
    k2_a2f<<<N_ * S_ * 8, 256, 0, stream>>>(spd, A3, A6, w1, b1, w2, b2, w4, b4, b3,
                                            alpha, beta, gamma, a2f, xm);
    k3_main<<<N_ * 24, 256, 0, stream>>>(xb, w3, dw, db, a2f, out, xd, stats);
    k4_coef<<<1, 256, 0, stream>>>(bn_w, bn_b, dbn_w, dbn_b, stats, coef);
    k5_final<<<4096, 256, 0, stream>>>(out, xd, coef);
}